// Round 8
// baseline (154.704 us; speedup 1.0000x reference)
//
#include <hip/hip_runtime.h>

#define S_TOTAL 17064
#define NB 16
#define NC 80
#define QPB 4266              // location-quads per batch image (sum hw/4)
#define NXQ 17                // quad-chunks of 256: 17*256=4352 >= 4266
#define NCCH 4                // class chunks of 20 classes each
#define NCH (NCCH + 1)        // + 1 cnt/reg chunk
#define TOTAL_BLOCKS (NXQ * NCH * NB)   // 1360
#define P1 TOTAL_BLOCKS
#define P2 (2 * TOTAL_BLOCKS)

typedef float vfloat4 __attribute__((ext_vector_type(4)));

struct Ptrs {
    const float* cls[5];
    const float* cnt[5];
    const float* reg[5];
    const float* cnt_t;   // [B,S,1]
    const float* reg_t;   // [B,S,4]
    const int*   cls_t;   // [B,S,1]
    float*       ws;      // 3 planes of TOTAL_BLOCKS floats: r0 | r1 | r2
    float*       out;
};

__device__ __forceinline__ float focal_term(float x, bool o) {
    const float xs = o ? x : -x;            // p_t = sigmoid(xs)
    const float af = o ? 0.25f : 0.75f;
    const float em = __expf(-xs);
    const float pt = 1.0f / (1.0f + em);
    const float q  = em * pt;               // 1 - p_t
    return af * q * q * __logf(1.0f + em);  // -af*(1-pt)^2*log(pt)
}

__device__ __forceinline__ float giou_term(float pl, float pt_, float pr, float pb,
                                           float tl, float tt, float tr, float tb) {
    const float overlap = fmaxf(fminf(pr, tr) + fminf(pl, tl), 0.0f) *
                          fmaxf(fminf(pb, tb) + fminf(pt_, tt), 0.0f);
    const float area1 = (pr + pl) * (pb + pt_);
    const float area2 = (tr + tl) * (tb + tt);
    const float uni = area1 + area2 - overlap;
    const float iou = overlap / uni;
    const float ga = fmaxf(fmaxf(pr, tr) + fmaxf(pl, tl), 0.0f) *
                     fmaxf(fmaxf(pb, tb) + fmaxf(pt_, tt), 0.0f);
    const float giou = iou - (ga - uni) / fmaxf(ga, 1e-10f);
    return 1.0f - giou;
}

__device__ __forceinline__ float bce_term(float x, float t) {
    return fmaxf(x, 0.0f) - x * t + __logf(1.0f + __expf(-fabsf(x)));
}

// grid: (NXQ, NCH, NB). ch<NCCH: 20-class focal chunk. ch==NCCH: cnt+GIoU.
// Explicit double-buffer (buf[4]+nxt[4] structurally live) is the ONLY lever
// that made the compiler hoist loads (r0: 112 VGPR). Simple loops got 32 VGPR
// + sunk loads in r1/r4/r5/r6 regardless of launch_bounds — attribute ceilings
// don't change the scheduler's sinking decision; structure does. 1360 blocks
// (5.3/CU) fix r0's 2.1-blocks/CU starvation. No atomics (r6: the ACQ_REL
// counter serialized blocks at ~65 ns each).
__global__ __launch_bounds__(256) void fcos_main(Ptrs p) {
    const int xq = blockIdx.x;              // 0..16 quad-chunk
    const int ch = blockIdx.y;              // 0..4
    const int b  = blockIdx.z;              // 0..15
    const int fq = xq * 256 + (int)threadIdx.x;  // flat quad id within image

    // flat quad -> (level, s0)
    int lvl, qb, hw, off;
    if (fq < 3200)      { lvl = 0; qb = 0;    hw = 12800; off = 0;     }
    else if (fq < 4000) { lvl = 1; qb = 3200; hw = 3200;  off = 12800; }
    else if (fq < 4200) { lvl = 2; qb = 4000; hw = 800;   off = 16000; }
    else if (fq < 4252) { lvl = 3; qb = 4200; hw = 208;   off = 16800; }
    else                { lvl = 4; qb = 4252; hw = 56;    off = 17008; }
    const bool active = (fq < QPB);

    float r0 = 0.f, r1 = 0.f, r2 = 0.f;     // cls | (cnt, reg, pos)

    if (active) {
        const int s0  = (fq - qb) << 2;
        const int gs0 = b * S_TOTAL + off + s0;

        if (ch < NCCH) {
            // ---- 20-class focal chunk, 4-wide double-buffered pipeline ----
            const int c0 = ch * 20;
            const int4 tq = *(const int4*)(p.cls_t + gs0);
            const float* cp = p.cls[lvl] + (size_t)((b * NC + c0) * hw + s0);

            vfloat4 buf[4];
            #pragma unroll
            for (int j = 0; j < 4; ++j)
                buf[j] = *(const vfloat4*)(cp + (size_t)(j * hw));

            float a0 = 0.f, a1 = 0.f, a2 = 0.f, a3 = 0.f;
            #pragma unroll
            for (int blk = 0; blk < 5; ++blk) {
                vfloat4 nxt[4];
                if (blk < 4) {
                    #pragma unroll
                    for (int j = 0; j < 4; ++j)
                        nxt[j] = *(const vfloat4*)(cp + (size_t)((blk * 4 + 4 + j) * hw));
                }
                #pragma unroll
                for (int j = 0; j < 4; ++j) {
                    const int c1 = c0 + blk * 4 + j + 1;
                    a0 += focal_term(buf[j].x, tq.x == c1);
                    a1 += focal_term(buf[j].y, tq.y == c1);
                    a2 += focal_term(buf[j].z, tq.z == c1);
                    a3 += focal_term(buf[j].w, tq.w == c1);
                }
                if (blk < 4) {
                    #pragma unroll
                    for (int j = 0; j < 4; ++j) buf[j] = nxt[j];
                }
            }
            r0 = (a0 + a1) + (a2 + a3);
        } else {
            // ---- cnt BCE + GIoU chunk ----
            const float4 tC  = *(const float4*)(p.cnt_t + gs0);
            const float4 xc  = *(const float4*)(p.cnt[lvl] + (size_t)(b * hw + s0));
            const float m0 = (tC.x > -1.0f) ? 1.0f : 0.0f;
            const float m1 = (tC.y > -1.0f) ? 1.0f : 0.0f;
            const float m2 = (tC.z > -1.0f) ? 1.0f : 0.0f;
            const float m3 = (tC.w > -1.0f) ? 1.0f : 0.0f;
            r2 = m0 + m1 + m2 + m3;
            r0 = bce_term(xc.x, tC.x) * m0 + bce_term(xc.y, tC.y) * m1 +
                 bce_term(xc.z, tC.z) * m2 + bce_term(xc.w, tC.w) * m3;

            const float* rp  = p.reg[lvl] + (size_t)(b * 4 * hw + s0);
            const float4 pl  = *(const float4*)(rp);
            const float4 pt_ = *(const float4*)(rp + (size_t)hw);
            const float4 pr  = *(const float4*)(rp + (size_t)(2 * hw));
            const float4 pb  = *(const float4*)(rp + (size_t)(3 * hw));
            const float4 t0  = *(const float4*)(p.reg_t + (size_t)(gs0 + 0) * 4);
            const float4 t1  = *(const float4*)(p.reg_t + (size_t)(gs0 + 1) * 4);
            const float4 t2  = *(const float4*)(p.reg_t + (size_t)(gs0 + 2) * 4);
            const float4 t3  = *(const float4*)(p.reg_t + (size_t)(gs0 + 3) * 4);

            r1 = giou_term(pl.x, pt_.x, pr.x, pb.x, t0.x, t0.y, t0.z, t0.w) * m0 +
                 giou_term(pl.y, pt_.y, pr.y, pb.y, t1.x, t1.y, t1.z, t1.w) * m1 +
                 giou_term(pl.z, pt_.z, pr.z, pb.z, t2.x, t2.y, t2.z, t2.w) * m2 +
                 giou_term(pl.w, pt_.w, pr.w, pb.w, t3.x, t3.y, t3.z, t3.w) * m3;
        }
    }

    // ---- block reduction (3 values) ----
    #pragma unroll
    for (int d = 32; d; d >>= 1) {
        r0 += __shfl_down(r0, d);
        r1 += __shfl_down(r1, d);
        r2 += __shfl_down(r2, d);
    }

    __shared__ float red[3][4];
    const int wave = threadIdx.x >> 6;
    const int lane = threadIdx.x & 63;
    if (lane == 0) {
        red[0][wave] = r0;
        red[1][wave] = r1;
        red[2][wave] = r2;
    }
    __syncthreads();
    if (threadIdx.x == 0) {
        // unique slots per block, plain cached stores -- no memset needed
        const int bid = xq + NXQ * (ch + NCH * b);
        p.ws[bid]      = red[0][0] + red[0][1] + red[0][2] + red[0][3];
        p.ws[P1 + bid] = red[1][0] + red[1][1] + red[1][2] + red[1][3];
        p.ws[P2 + bid] = red[2][0] + red[2][1] + red[2][2] + red[2][3];
    }
}

// Single-block finalize: reduces 3 planes of TOTAL_BLOCKS partials.
// Kernel boundary (same stream) guarantees visibility of fcos_main's stores.
__global__ __launch_bounds__(512) void fcos_finalize(const float* __restrict__ ws,
                                                     float* __restrict__ out) {
    __shared__ float sA[NB * NCH];   // 80 per-(b,ch) partials
    __shared__ float sB[NB * NCH];
    __shared__ float sC[NB * NCH];
    __shared__ float lb[3][NB];
    const int t = (int)threadIdx.x;

    if (t < NB * NCH) {
        const int b = t / NCH, ch = t - b * NCH;
        const int base = NXQ * (ch + NCH * b);
        float q0 = 0.f, q1 = 0.f, q2 = 0.f;
        #pragma unroll
        for (int xq = 0; xq < NXQ; ++xq) {
            q0 += ws[base + xq];
            q1 += ws[P1 + base + xq];
            q2 += ws[P2 + base + xq];
        }
        sA[t] = q0; sB[t] = q1; sC[t] = q2;
    }
    __syncthreads();

    if (t < NB) {
        const int rowbase = t * NCH;
        float cls = 0.f, reg = 0.f, pos = 0.f;
        #pragma unroll
        for (int ch = 0; ch < NCCH; ++ch) cls += sA[rowbase + ch];
        const float cnt = sA[rowbase + NCCH];
        #pragma unroll
        for (int ch = 0; ch < NCH; ++ch) { reg += sB[rowbase + ch]; pos += sC[rowbase + ch]; }
        const float np = fmaxf(pos, 1.0f);
        lb[0][t] = cls / np;
        lb[1][t] = cnt / np;
        lb[2][t] = reg / np;
    }
    __syncthreads();

    if (t == 0) {
        float l0 = 0.f, l1 = 0.f, l2 = 0.f;
        #pragma unroll
        for (int b = 0; b < NB; ++b) {
            l0 += lb[0][b]; l1 += lb[1][b]; l2 += lb[2][b];
        }
        l0 *= (1.0f / NB); l1 *= (1.0f / NB); l2 *= (1.0f / NB);
        out[0] = l0;
        out[1] = l1;
        out[2] = l2;
        out[3] = l0 + l1 + l2;
    }
}

extern "C" void kernel_launch(void* const* d_in, const int* in_sizes, int n_in,
                              void* d_out, int out_size, void* d_ws, size_t ws_size,
                              hipStream_t stream) {
    Ptrs p;
    for (int i = 0; i < 5; ++i) {
        p.cls[i] = (const float*)d_in[3 * i + 0];
        p.cnt[i] = (const float*)d_in[3 * i + 1];
        p.reg[i] = (const float*)d_in[3 * i + 2];
    }
    p.cnt_t = (const float*)d_in[15];
    p.reg_t = (const float*)d_in[16];
    p.cls_t = (const int*)  d_in[17];
    p.ws    = (float*)d_ws;
    p.out   = (float*)d_out;

    dim3 grid(NXQ, NCH, NB);   // 1360 workgroups
    fcos_main<<<grid, 256, 0, stream>>>(p);
    fcos_finalize<<<dim3(1), 512, 0, stream>>>((const float*)d_ws, (float*)d_out);
}

// Round 9
// 149.135 us; speedup vs baseline: 1.0373x; 1.0373x over previous
//
#include <hip/hip_runtime.h>

#define S_TOTAL 17064
#define NB 16
#define NC 80
#define QPB 4266              // location-quads per batch image (sum hw/4)
#define NXQ 17                // quad-chunks of 256: 17*256=4352 >= 4266
#define NJ 7                  // class-groups per (b,xq): 6x12 classes + (8 classes + cnt/reg)
#define TOTAL_BLOCKS (NB * NJ * NXQ)    // 1904 == exactly-resident (8 blocks/CU x 238 CUs used)
#define PL TOTAL_BLOCKS       // plane stride: cls | cnt | reg | pos

typedef float vfloat4 __attribute__((ext_vector_type(4)));

struct Ptrs {
    const float* cls[5];
    const float* cnt[5];
    const float* reg[5];
    const float* cnt_t;   // [B,S,1]
    const float* reg_t;   // [B,S,4]
    const int*   cls_t;   // [B,S,1] (int32 on device: jax x64 disabled)
    float*       ws;      // 4 planes of TOTAL_BLOCKS floats
    float*       out;
};

__device__ __forceinline__ float focal_term(float x, bool o) {
    const float xs = o ? x : -x;            // p_t = sigmoid(xs)
    const float af = o ? 0.25f : 0.75f;
    const float em = __expf(-xs);
    const float pt = 1.0f / (1.0f + em);
    const float q  = em * pt;               // 1 - p_t
    return af * q * q * __logf(1.0f + em);  // -af*(1-pt)^2*log(pt)
}

__device__ __forceinline__ float giou_term(float pl, float pt_, float pr, float pb,
                                           float tl, float tt, float tr, float tb) {
    const float overlap = fmaxf(fminf(pr, tr) + fminf(pl, tl), 0.0f) *
                          fmaxf(fminf(pb, tb) + fminf(pt_, tt), 0.0f);
    const float area1 = (pr + pl) * (pb + pt_);
    const float area2 = (tr + tl) * (tb + tt);
    const float uni = area1 + area2 - overlap;
    const float iou = overlap / uni;
    const float ga = fmaxf(fmaxf(pr, tr) + fmaxf(pl, tl), 0.0f) *
                     fmaxf(fmaxf(pb, tb) + fmaxf(pt_, tt), 0.0f);
    const float giou = iou - (ga - uni) / fmaxf(ga, 1e-10f);
    return 1.0f - giou;
}

__device__ __forceinline__ float bce_term(float x, float t) {
    return fmaxf(x, 0.0f) - x * t + __logf(1.0f + __expf(-fabsf(x)));
}

// 1904 blocks = 16b x 7j x 17xq, ALL resident simultaneously (<=2048 capacity
// at VGPR<=64): r8 showed main's gap is idle issue slots -- 2.6 waves/SIMD
// time-avg (Occ 32%) x ~15% per-wave duty = VALUBusy 39%. 8 resident waves/SIMD
// saturate the pipe; latency hiding comes from TLP, not per-wave MLP (the
// allocator sinks loads at its 32-40 VGPR choice regardless of structure --
// r1/r4/r5/r8). j<6: 12 focal classes; j==6: 8 classes + cnt/GIoU. tq and
// level-classification amortized over the whole class group. No atomics
// (r6: single-address ACQ_REL counter serialized blocks at ~65ns each).
__global__ __launch_bounds__(256) void fcos_main(Ptrs p) {
    const int bid = (int)blockIdx.x;        // 0..1903
    const int b   = bid / (NJ * NXQ);       // 0..15
    const int r   = bid - b * (NJ * NXQ);
    const int j   = r / NXQ;                // 0..6
    const int xq  = r - j * NXQ;            // 0..16
    const int fq  = xq * 256 + (int)threadIdx.x;

    // flat quad -> (level, s0)
    int lvl, qb, hw, off;
    if (fq < 3200)      { lvl = 0; qb = 0;    hw = 12800; off = 0;     }
    else if (fq < 4000) { lvl = 1; qb = 3200; hw = 3200;  off = 12800; }
    else if (fq < 4200) { lvl = 2; qb = 4000; hw = 800;   off = 16000; }
    else if (fq < 4252) { lvl = 3; qb = 4200; hw = 208;   off = 16800; }
    else                { lvl = 4; qb = 4252; hw = 56;    off = 17008; }
    const bool active = (fq < QPB);

    float acls = 0.f, acnt = 0.f, areg = 0.f, apos = 0.f;

    if (active) {
        const int s0  = (fq - qb) << 2;
        const int gs0 = b * S_TOTAL + off + s0;
        const int4 tq = *(const int4*)(p.cls_t + gs0);

        // ---- focal classes [12j, 12j+ncls) ----
        const int cbase = j * 12;
        const int ncls  = (j < 6) ? 12 : 8;          // wave-uniform trip
        const float* cp = p.cls[lvl] + (size_t)((b * NC + cbase) * hw + s0);

        float a0 = 0.f, a1 = 0.f, a2 = 0.f, a3 = 0.f;
        #pragma unroll 4
        for (int c = 0; c < ncls; ++c) {
            const vfloat4 v = *(const vfloat4*)(cp + (size_t)(c * hw));
            const int c1 = cbase + c + 1;
            a0 += focal_term(v.x, tq.x == c1);
            a1 += focal_term(v.y, tq.y == c1);
            a2 += focal_term(v.z, tq.z == c1);
            a3 += focal_term(v.w, tq.w == c1);
        }
        acls = (a0 + a1) + (a2 + a3);

        if (j == 6) {
            // ---- cnt BCE + GIoU unit (once per (b,xq)) ----
            const float4 tC  = *(const float4*)(p.cnt_t + gs0);
            const float4 xc  = *(const float4*)(p.cnt[lvl] + (size_t)(b * hw + s0));
            const float m0 = (tC.x > -1.0f) ? 1.0f : 0.0f;
            const float m1 = (tC.y > -1.0f) ? 1.0f : 0.0f;
            const float m2 = (tC.z > -1.0f) ? 1.0f : 0.0f;
            const float m3 = (tC.w > -1.0f) ? 1.0f : 0.0f;
            apos = m0 + m1 + m2 + m3;
            acnt = bce_term(xc.x, tC.x) * m0 + bce_term(xc.y, tC.y) * m1 +
                   bce_term(xc.z, tC.z) * m2 + bce_term(xc.w, tC.w) * m3;

            const float* rp  = p.reg[lvl] + (size_t)(b * 4 * hw + s0);
            const float4 pl  = *(const float4*)(rp);
            const float4 pt_ = *(const float4*)(rp + (size_t)hw);
            const float4 pr  = *(const float4*)(rp + (size_t)(2 * hw));
            const float4 pb  = *(const float4*)(rp + (size_t)(3 * hw));
            const float4 t0  = *(const float4*)(p.reg_t + (size_t)(gs0 + 0) * 4);
            const float4 t1  = *(const float4*)(p.reg_t + (size_t)(gs0 + 1) * 4);
            const float4 t2  = *(const float4*)(p.reg_t + (size_t)(gs0 + 2) * 4);
            const float4 t3  = *(const float4*)(p.reg_t + (size_t)(gs0 + 3) * 4);

            areg = giou_term(pl.x, pt_.x, pr.x, pb.x, t0.x, t0.y, t0.z, t0.w) * m0 +
                   giou_term(pl.y, pt_.y, pr.y, pb.y, t1.x, t1.y, t1.z, t1.w) * m1 +
                   giou_term(pl.z, pt_.z, pr.z, pb.z, t2.x, t2.y, t2.z, t2.w) * m2 +
                   giou_term(pl.w, pt_.w, pr.w, pb.w, t3.x, t3.y, t3.z, t3.w) * m3;
        }
    }

    // ---- block reduction (4 values) ----
    #pragma unroll
    for (int d = 32; d; d >>= 1) {
        acls += __shfl_down(acls, d);
        acnt += __shfl_down(acnt, d);
        areg += __shfl_down(areg, d);
        apos += __shfl_down(apos, d);
    }

    __shared__ float red[4][4];
    const int wave = threadIdx.x >> 6;
    const int lane = threadIdx.x & 63;
    if (lane == 0) {
        red[0][wave] = acls;
        red[1][wave] = acnt;
        red[2][wave] = areg;
        red[3][wave] = apos;
    }
    __syncthreads();
    if (threadIdx.x == 0) {
        // unique slots per block, plain cached stores (no memset, no atomics)
        p.ws[bid]          = red[0][0] + red[0][1] + red[0][2] + red[0][3];
        p.ws[PL + bid]     = red[1][0] + red[1][1] + red[1][2] + red[1][3];
        p.ws[2 * PL + bid] = red[2][0] + red[2][1] + red[2][2] + red[2][3];
        p.ws[3 * PL + bid] = red[3][0] + red[3][1] + red[3][2] + red[3][3];
    }
}

// Single-block finalize. Kernel boundary (same stream) orders fcos_main's stores.
// Per-b slots are contiguous: b owns [b*119, (b+1)*119).
__global__ __launch_bounds__(256) void fcos_finalize(const float* __restrict__ ws,
                                                     float* __restrict__ out) {
    __shared__ float s[4][256];
    __shared__ float lb[3][NB];
    const int t = (int)threadIdx.x;
    const int b = t >> 4;                   // 0..15
    const int k = t & 15;                   // 0..15

    float q0 = 0.f, q1 = 0.f, q2 = 0.f, q3 = 0.f;
    for (int i = k; i < NJ * NXQ; i += 16) {   // 119 slots per b
        const int slot = b * (NJ * NXQ) + i;
        q0 += ws[slot];
        q1 += ws[PL + slot];
        q2 += ws[2 * PL + slot];
        q3 += ws[3 * PL + slot];
    }
    s[0][t] = q0; s[1][t] = q1; s[2][t] = q2; s[3][t] = q3;
    __syncthreads();

    if (t < NB) {
        float cls = 0.f, cnt = 0.f, reg = 0.f, pos = 0.f;
        #pragma unroll
        for (int kk = 0; kk < 16; ++kk) {
            cls += s[0][t * 16 + kk];
            cnt += s[1][t * 16 + kk];
            reg += s[2][t * 16 + kk];
            pos += s[3][t * 16 + kk];
        }
        const float np = fmaxf(pos, 1.0f);
        lb[0][t] = cls / np;
        lb[1][t] = cnt / np;
        lb[2][t] = reg / np;
    }
    __syncthreads();

    if (t == 0) {
        float l0 = 0.f, l1 = 0.f, l2 = 0.f;
        #pragma unroll
        for (int bb = 0; bb < NB; ++bb) {
            l0 += lb[0][bb]; l1 += lb[1][bb]; l2 += lb[2][bb];
        }
        l0 *= (1.0f / NB); l1 *= (1.0f / NB); l2 *= (1.0f / NB);
        out[0] = l0;
        out[1] = l1;
        out[2] = l2;
        out[3] = l0 + l1 + l2;
    }
}

extern "C" void kernel_launch(void* const* d_in, const int* in_sizes, int n_in,
                              void* d_out, int out_size, void* d_ws, size_t ws_size,
                              hipStream_t stream) {
    Ptrs p;
    for (int i = 0; i < 5; ++i) {
        p.cls[i] = (const float*)d_in[3 * i + 0];
        p.cnt[i] = (const float*)d_in[3 * i + 1];
        p.reg[i] = (const float*)d_in[3 * i + 2];
    }
    p.cnt_t = (const float*)d_in[15];
    p.reg_t = (const float*)d_in[16];
    p.cls_t = (const int*)  d_in[17];
    p.ws    = (float*)d_ws;
    p.out   = (float*)d_out;

    fcos_main<<<dim3(TOTAL_BLOCKS), 256, 0, stream>>>(p);
    fcos_finalize<<<dim3(1), 256, 0, stream>>>((const float*)d_ws, (float*)d_out);
}